// Round 10
// baseline (275.971 us; speedup 1.0000x reference)
//
#include <hip/hip_runtime.h>

#define NB 4
#define NT 40000
#define NS0 30000
#define ND0 15000
#define NE0 360000
#define ND1 7500
#define NE1 180000
#define NEG 0.2f

typedef __attribute__((ext_vector_type(8))) short bf8;
typedef __attribute__((ext_vector_type(4))) float f4;

__device__ __forceinline__ unsigned short f2bf(float f) {
    unsigned u = __float_as_uint(f);
    u += 0x7FFF + ((u >> 16) & 1);          // round-to-nearest-even
    return (unsigned short)(u >> 16);
}
// packed bf16 pair in a uint: low ushort = even channel, high = odd channel
__device__ __forceinline__ float bf_lo(unsigned u) { return __uint_as_float(u << 16); }
__device__ __forceinline__ float bf_hi(unsigned u) { return __uint_as_float(u & 0xFFFF0000u); }

// ---------------- zero degree histograms -----------------------------------
__global__ void kz_zero(int* __restrict__ deg0, int* __restrict__ deg1) {
    int t = blockIdx.x * blockDim.x + threadIdx.x;
    if (t < ND0) deg0[t] = 0;
    if (t < ND1) deg1[t] = 0;
}

// ---------------- histogram of edge destinations ---------------------------
__global__ void kh_hist(const int* __restrict__ edst0, const int* __restrict__ edst1,
                        int* __restrict__ deg0, int* __restrict__ deg1) {
    int t = blockIdx.x * blockDim.x + threadIdx.x;
    if (t < NE0) atomicAdd(&deg0[edst0[t]], 1);
    else if (t < NE0 + NE1) atomicAdd(&deg1[edst1[t - NE0]], 1);
}

// ---------------- exclusive scan (one block per layer) ---------------------
__device__ void scan_block(const int* __restrict__ deg, int* __restrict__ off,
                           int* __restrict__ cur, int n) {
    __shared__ int s[1024];
    int t = threadIdx.x;
    int chunk = (n + 1023) / 1024;
    int base = t * chunk;
    int mysum = 0;
    for (int i = 0; i < chunk; ++i) {
        int idx = base + i;
        if (idx < n) mysum += deg[idx];
    }
    s[t] = mysum;
    __syncthreads();
    for (int o = 1; o < 1024; o <<= 1) {
        int v = (t >= o) ? s[t - o] : 0;
        __syncthreads();
        s[t] += v;
        __syncthreads();
    }
    int run = s[t] - mysum;   // exclusive prefix of my chunk
    for (int i = 0; i < chunk; ++i) {
        int idx = base + i;
        if (idx < n) {
            off[idx] = run;
            cur[idx] = run;
            run += deg[idx];
        }
    }
}

__global__ void ks_scan(const int* __restrict__ deg0, int* __restrict__ off0, int* __restrict__ cur0,
                        const int* __restrict__ deg1, int* __restrict__ off1, int* __restrict__ cur1) {
    if (blockIdx.x == 0) scan_block(deg0, off0, cur0, ND0);
    else                 scan_block(deg1, off1, cur1, ND1);
}

// ---------------- scatter src ids into dst-sorted order --------------------
__global__ void kc_scatter(const int* __restrict__ esrc0, const int* __restrict__ edst0,
                           const int* __restrict__ esrc1, const int* __restrict__ edst1,
                           int* __restrict__ cur0, int* __restrict__ cur1,
                           int* __restrict__ srcsort0, int* __restrict__ srcsort1) {
    int t = blockIdx.x * blockDim.x + threadIdx.x;
    if (t < NE0) {
        int pos = atomicAdd(&cur0[edst0[t]], 1);
        srcsort0[pos] = esrc0[t];
    } else if (t < NE0 + NE1) {
        int e = t - NE0;
        int pos = atomicAdd(&cur1[edst1[e]], 1);
        srcsort1[pos] = esrc1[e];
    }
}

// ---------------- layer 1 node transform (MFMA bf16 GEMM) ------------------
__global__ __launch_bounds__(256) void k1_node1(
        const float* __restrict__ x, const int* __restrict__ n_id0,
        const float* __restrict__ W1, const float* __restrict__ a_src,
        const float* __restrict__ a_dst,
        unsigned short* __restrict__ ht1b, float* __restrict__ es1, float* __restrict__ ed1) {
    __shared__ unsigned short xtb[64*72];
    __shared__ unsigned short wtb[64*72];
    __shared__ float asl[64], adl[64];
    int t = threadIdx.x;
    {
        int k = t >> 2, nb = (t & 3) * 16;
        const float* wrow = &W1[k*64 + nb];
        #pragma unroll
        for (int j = 0; j < 16; j += 4) {
            float4 v = *(const float4*)&wrow[j];
            wtb[(nb+j+0)*72 + k] = f2bf(v.x);
            wtb[(nb+j+1)*72 + k] = f2bf(v.y);
            wtb[(nb+j+2)*72 + k] = f2bf(v.z);
            wtb[(nb+j+3)*72 + k] = f2bf(v.w);
        }
    }
    if (t < 64) { asl[t] = a_src[t]; adl[t] = a_dst[t]; }
    {
        int rr = t & 63;
        int q4 = t >> 6;
        int row_s = blockIdx.x * 64 + rr;           // < 120000 (1875*64)
        int bs = row_s / NS0;
        int ns = row_s - bs * NS0;
        const float* xrow = x + ((size_t)(bs * NT + n_id0[ns])) * 64;
        #pragma unroll
        for (int j = 0; j < 4; ++j) {
            int k = q4 * 16 + j * 4;
            float4 v = *(const float4*)&xrow[k];
            ushort4 u;
            u.x = f2bf(v.x); u.y = f2bf(v.y); u.z = f2bf(v.z); u.w = f2bf(v.w);
            *(ushort4*)&xtb[rr*72 + k] = u;
        }
    }
    __syncthreads();
    int w = t >> 6, lane = t & 63, quad = lane >> 4, cl = lane & 15;
    int arow = 16*w + cl;
    bf8 a0 = *(const bf8*)&xtb[arow*72 + quad*8];        // A[m=cl][k=quad*8+j]
    bf8 a1 = *(const bf8*)&xtb[arow*72 + 32 + quad*8];   // k+32
    f4 acc[4];
    #pragma unroll
    for (int sub = 0; sub < 4; ++sub) {
        int n = sub*16 + cl;
        bf8 b0 = *(const bf8*)&wtb[n*72 + quad*8];       // B[k][n=cl]
        bf8 b1 = *(const bf8*)&wtb[n*72 + 32 + quad*8];
        f4 c = {0.f, 0.f, 0.f, 0.f};
        c = __builtin_amdgcn_mfma_f32_16x16x32_bf16(a0, b0, c, 0, 0, 0);
        c = __builtin_amdgcn_mfma_f32_16x16x32_bf16(a1, b1, c, 0, 0, 0);
        acc[sub] = c;
    }
    int rbase = blockIdx.x*64 + 16*w + quad*4;
    #pragma unroll
    for (int sub = 0; sub < 4; ++sub)
        #pragma unroll
        for (int r = 0; r < 4; ++r)
            ht1b[(size_t)(rbase + r)*64 + sub*16 + cl] = f2bf(acc[sub][r]);
    #pragma unroll
    for (int r = 0; r < 4; ++r) {
        #pragma unroll
        for (int sub = 0; sub < 4; ++sub) {
            int col = sub*16 + cl;
            float ps = acc[sub][r] * asl[col];
            float pd = acc[sub][r] * adl[col];
            ps += __shfl_xor(ps, 1); ps += __shfl_xor(ps, 2); ps += __shfl_xor(ps, 4);
            pd += __shfl_xor(pd, 1); pd += __shfl_xor(pd, 2); pd += __shfl_xor(pd, 4);
            if ((cl & 7) == 0) {
                int h = sub*2 + (cl >> 3);
                es1[(rbase + r)*8 + h] = ps;
                ed1[(rbase + r)*8 + h] = pd;
            }
        }
    }
}

// ---------------- layer 1 per-dst aggregation (8 lanes / dst, no shfl) -----
// lane = 1 head = 8 channels (uint4 16B bf16). Each lane owns its head's
// full softmax state -> zero cross-lane reduction. Wave = 8 dsts,
// block = 32 dsts x 1 batch (batch-major for L2). 2-deep unroll + prefetch.
#define K3CH ((ND0 + 31) / 32)
__global__ __launch_bounds__(256) void k3_agg1(
        const int* __restrict__ srcsort0, const int* __restrict__ off0,
        const int* __restrict__ deg0, const int* __restrict__ res0,
        const float* __restrict__ es1, const float* __restrict__ ed1,
        const unsigned short* __restrict__ ht1b, const float* __restrict__ b1,
        float* __restrict__ agg1) {
    int b = blockIdx.x / K3CH;
    int chunk = blockIdx.x - b * K3CH;
    int d = chunk * 32 + (threadIdx.x >> 3);
    int c = threadIdx.x & 7;               // head; channels 8c..8c+7
    bool valid = d < ND0;
    int dn = valid ? res0[d] : 0;
    float edv = ed1[(b*NS0 + dn)*8 + c];
    int start = valid ? off0[d] : 0;
    int cnt = valid ? deg0[d] : 0;
    float acc[8] = {};
    float wsum = 0.f;
    int i = 0;
    int sA = (0 < cnt) ? srcsort0[start] : 0;
    int sB = (1 < cnt) ? srcsort0[start + 1] : 0;
    while (i + 1 < cnt) {
        int pA = (i + 2 < cnt) ? srcsort0[start + i + 2] : 0;
        int pB = (i + 3 < cnt) ? srcsort0[start + i + 3] : 0;
        float e0 = es1[(b*NS0 + sA)*8 + c] + edv;
        float e1 = es1[(b*NS0 + sB)*8 + c] + edv;
        uint4 h0 = *(const uint4*)&ht1b[((size_t)(b*NS0 + sA))*64 + c*8];
        uint4 h1 = *(const uint4*)&ht1b[((size_t)(b*NS0 + sB))*64 + c*8];
        e0 = e0 > 0.f ? e0 : NEG * e0;
        e1 = e1 > 0.f ? e1 : NEG * e1;
        float w0 = __expf(e0), w1 = __expf(e1);
        acc[0] = fmaf(w0, bf_lo(h0.x), acc[0]); acc[1] = fmaf(w0, bf_hi(h0.x), acc[1]);
        acc[2] = fmaf(w0, bf_lo(h0.y), acc[2]); acc[3] = fmaf(w0, bf_hi(h0.y), acc[3]);
        acc[4] = fmaf(w0, bf_lo(h0.z), acc[4]); acc[5] = fmaf(w0, bf_hi(h0.z), acc[5]);
        acc[6] = fmaf(w0, bf_lo(h0.w), acc[6]); acc[7] = fmaf(w0, bf_hi(h0.w), acc[7]);
        acc[0] = fmaf(w1, bf_lo(h1.x), acc[0]); acc[1] = fmaf(w1, bf_hi(h1.x), acc[1]);
        acc[2] = fmaf(w1, bf_lo(h1.y), acc[2]); acc[3] = fmaf(w1, bf_hi(h1.y), acc[3]);
        acc[4] = fmaf(w1, bf_lo(h1.z), acc[4]); acc[5] = fmaf(w1, bf_hi(h1.z), acc[5]);
        acc[6] = fmaf(w1, bf_lo(h1.w), acc[6]); acc[7] = fmaf(w1, bf_hi(h1.w), acc[7]);
        wsum += w0 + w1;
        sA = pA; sB = pB; i += 2;
    }
    if (i < cnt) {
        float e0 = es1[(b*NS0 + sA)*8 + c] + edv;
        uint4 h0 = *(const uint4*)&ht1b[((size_t)(b*NS0 + sA))*64 + c*8];
        e0 = e0 > 0.f ? e0 : NEG * e0;
        float w0 = __expf(e0);
        acc[0] = fmaf(w0, bf_lo(h0.x), acc[0]); acc[1] = fmaf(w0, bf_hi(h0.x), acc[1]);
        acc[2] = fmaf(w0, bf_lo(h0.y), acc[2]); acc[3] = fmaf(w0, bf_hi(h0.y), acc[3]);
        acc[4] = fmaf(w0, bf_lo(h0.z), acc[4]); acc[5] = fmaf(w0, bf_hi(h0.z), acc[5]);
        acc[6] = fmaf(w0, bf_lo(h0.w), acc[6]); acc[7] = fmaf(w0, bf_hi(h0.w), acc[7]);
        wsum += w0;
    }
    if (valid) {
        float inv = cnt > 0 ? 1.f / wsum : 0.f;
        float4 b_lo = *(const float4*)&b1[c*8];
        float4 b_hi = *(const float4*)&b1[c*8 + 4];
        float o[8];
        o[0] = acc[0]*inv + b_lo.x; o[1] = acc[1]*inv + b_lo.y;
        o[2] = acc[2]*inv + b_lo.z; o[3] = acc[3]*inv + b_lo.w;
        o[4] = acc[4]*inv + b_hi.x; o[5] = acc[5]*inv + b_hi.y;
        o[6] = acc[6]*inv + b_hi.z; o[7] = acc[7]*inv + b_hi.w;
        #pragma unroll
        for (int j = 0; j < 8; ++j) o[j] = o[j] > 0.f ? o[j] : __expf(o[j]) - 1.f;
        float* orow = &agg1[((size_t)(b*ND0 + d))*64 + c*8];
        *(float4*)&orow[0] = make_float4(o[0], o[1], o[2], o[3]);
        *(float4*)&orow[4] = make_float4(o[4], o[5], o[6], o[7]);
    }
}

// ---------------- layer 2 node transform (register-blocked GEMM) -----------
__global__ __launch_bounds__(256) void k5_node2(
        const float* __restrict__ h, const float* __restrict__ W2,
        const float* __restrict__ a_src2, const float* __restrict__ a_dst2,
        float* __restrict__ ht2, float* __restrict__ es2, float* __restrict__ ed2) {
    __shared__ float xt[64*132];
    __shared__ float Wl[64*32];
    __shared__ float as2[32], ad2[32];
    int t = threadIdx.x;
    for (int i = t; i < 512; i += 256)
        *(float4*)&Wl[i*4] = *(const float4*)&W2[i*4];
    if (t < 32) { as2[t] = a_src2[t]; ad2[t] = a_dst2[t]; }
    int rr = t & 127;
    int q  = t >> 7;
    int row_s = blockIdx.x * 128 + rr;
    bool valid = row_s < NB*ND0;
    const float* hrow = h + (size_t)row_s * 64;
    #pragma unroll
    for (int j = 0; j < 8; ++j) {
        int k = q * 32 + j * 4;
        float4 v = valid ? *(const float4*)&hrow[k] : make_float4(0.f,0.f,0.f,0.f);
        xt[(k+0)*132 + rr] = v.x;
        xt[(k+1)*132 + rr] = v.y;
        xt[(k+2)*132 + rr] = v.z;
        xt[(k+3)*132 + rr] = v.w;
    }
    __syncthreads();
    int c0 = (t & 7) * 4;
    int r0 = (t >> 3) * 4;
    float acc[4][4] = {};
    #pragma unroll 16
    for (int k = 0; k < 64; ++k) {
        float4 a = *(const float4*)&xt[k*132 + r0];
        float4 w = *(const float4*)&Wl[k*32 + c0];
        acc[0][0] = fmaf(a.x, w.x, acc[0][0]); acc[0][1] = fmaf(a.x, w.y, acc[0][1]);
        acc[0][2] = fmaf(a.x, w.z, acc[0][2]); acc[0][3] = fmaf(a.x, w.w, acc[0][3]);
        acc[1][0] = fmaf(a.y, w.x, acc[1][0]); acc[1][1] = fmaf(a.y, w.y, acc[1][1]);
        acc[1][2] = fmaf(a.y, w.z, acc[1][2]); acc[1][3] = fmaf(a.y, w.w, acc[1][3]);
        acc[2][0] = fmaf(a.z, w.x, acc[2][0]); acc[2][1] = fmaf(a.z, w.y, acc[2][1]);
        acc[2][2] = fmaf(a.z, w.z, acc[2][2]); acc[2][3] = fmaf(a.z, w.w, acc[2][3]);
        acc[3][0] = fmaf(a.w, w.x, acc[3][0]); acc[3][1] = fmaf(a.w, w.y, acc[3][1]);
        acc[3][2] = fmaf(a.w, w.z, acc[3][2]); acc[3][3] = fmaf(a.w, w.w, acc[3][3]);
    }
    float s0 = as2[c0], s1 = as2[c0+1], s2 = as2[c0+2], s3 = as2[c0+3];
    float d0 = ad2[c0], d1 = ad2[c0+1], d2 = ad2[c0+2], d3 = ad2[c0+3];
    #pragma unroll
    for (int i = 0; i < 4; ++i) {
        int row = blockIdx.x * 128 + r0 + i;
        float ps = acc[i][0]*s0 + acc[i][1]*s1 + acc[i][2]*s2 + acc[i][3]*s3;
        float pd = acc[i][0]*d0 + acc[i][1]*d1 + acc[i][2]*d2 + acc[i][3]*d3;
        ps += __shfl_xor(ps, 1); ps += __shfl_xor(ps, 2); ps += __shfl_xor(ps, 4);
        pd += __shfl_xor(pd, 1); pd += __shfl_xor(pd, 2); pd += __shfl_xor(pd, 4);
        if (row < NB*ND0) {
            *(float4*)&ht2[(size_t)row*32 + c0] =
                make_float4(acc[i][0], acc[i][1], acc[i][2], acc[i][3]);
            if ((t & 7) == 0) { es2[row] = ps; ed2[row] = pd; }
        }
    }
}

// ---------------- layer 2 per-dst aggregation (8 lanes / dst, no shfl) -----
// lane = 4 channels (float4); 8 lanes cover all 32 channels; H2=1 so the
// softmax weight is identical across lanes (recomputed, no sharing needed).
#define K7CH ((ND1 + 31) / 32)
__global__ __launch_bounds__(256) void k7_agg2(
        const int* __restrict__ srcsort1, const int* __restrict__ off1,
        const int* __restrict__ deg1, const int* __restrict__ res1,
        const float* __restrict__ es2, const float* __restrict__ ed2,
        const float* __restrict__ ht2, const float* __restrict__ b2,
        float* __restrict__ outp) {
    int b = blockIdx.x / K7CH;
    int chunk = blockIdx.x - b * K7CH;
    int d = chunk * 32 + (threadIdx.x >> 3);
    int c = threadIdx.x & 7;               // channel quad: 4c..4c+3
    bool valid = d < ND1;
    int dn = valid ? res1[d] : 0;
    float edv = ed2[b*ND0 + dn];
    int start = valid ? off1[d] : 0;
    int cnt = valid ? deg1[d] : 0;
    float ax = 0.f, ay = 0.f, az = 0.f, aw = 0.f, wsum = 0.f;
    int i = 0;
    int sA = (0 < cnt) ? srcsort1[start] : 0;
    int sB = (1 < cnt) ? srcsort1[start + 1] : 0;
    while (i + 1 < cnt) {
        int pA = (i + 2 < cnt) ? srcsort1[start + i + 2] : 0;
        int pB = (i + 3 < cnt) ? srcsort1[start + i + 3] : 0;
        float lg0 = es2[b*ND0 + sA] + edv;
        float lg1 = es2[b*ND0 + sB] + edv;
        float4 h0 = *(const float4*)&ht2[((size_t)(b*ND0 + sA))*32 + c*4];
        float4 h1 = *(const float4*)&ht2[((size_t)(b*ND0 + sB))*32 + c*4];
        lg0 = lg0 > 0.f ? lg0 : NEG * lg0;
        lg1 = lg1 > 0.f ? lg1 : NEG * lg1;
        float w0 = __expf(lg0), w1 = __expf(lg1);
        ax = fmaf(w0, h0.x, ax); ay = fmaf(w0, h0.y, ay);
        az = fmaf(w0, h0.z, az); aw = fmaf(w0, h0.w, aw);
        ax = fmaf(w1, h1.x, ax); ay = fmaf(w1, h1.y, ay);
        az = fmaf(w1, h1.z, az); aw = fmaf(w1, h1.w, aw);
        wsum += w0 + w1;
        sA = pA; sB = pB; i += 2;
    }
    if (i < cnt) {
        float lg0 = es2[b*ND0 + sA] + edv;
        float4 h0 = *(const float4*)&ht2[((size_t)(b*ND0 + sA))*32 + c*4];
        lg0 = lg0 > 0.f ? lg0 : NEG * lg0;
        float w0 = __expf(lg0);
        ax = fmaf(w0, h0.x, ax); ay = fmaf(w0, h0.y, ay);
        az = fmaf(w0, h0.z, az); aw = fmaf(w0, h0.w, aw);
        wsum += w0;
    }
    if (valid) {
        float inv = cnt > 0 ? 1.f / wsum : 0.f;
        float4 bb = *(const float4*)&b2[c*4];
        float4 o;
        o.x = ax*inv + bb.x; o.y = ay*inv + bb.y;
        o.z = az*inv + bb.z; o.w = aw*inv + bb.w;
        *(float4*)&outp[((size_t)(b*ND1 + d))*32 + c*4] = o;
    }
}

extern "C" void kernel_launch(void* const* d_in, const int* in_sizes, int n_in,
                              void* d_out, int out_size, void* d_ws, size_t ws_size,
                              hipStream_t stream) {
    const float* x        = (const float*)d_in[0];
    const int*   n_id0    = (const int*)d_in[1];
    const int*   res0     = (const int*)d_in[2];
    const int*   esrc0    = (const int*)d_in[3];
    const int*   edst0    = (const int*)d_in[4];
    const int*   res1     = (const int*)d_in[5];
    const int*   esrc1    = (const int*)d_in[6];
    const int*   edst1    = (const int*)d_in[7];
    const float* W1       = (const float*)d_in[8];
    const float* a_src1   = (const float*)d_in[9];
    const float* a_dst1   = (const float*)d_in[10];
    const float* b1       = (const float*)d_in[11];
    const float* W2       = (const float*)d_in[12];
    const float* a_src2   = (const float*)d_in[13];
    const float* a_dst2   = (const float*)d_in[14];
    const float* b2       = (const float*)d_in[15];
    float* outp = (float*)d_out;

    char* base = (char*)d_ws;
    unsigned short* ht1b = (unsigned short*)base;            // 120000*64*2  = 15,360,000 B
    float* es1  = (float*)(base + 15360000);                 // 960,000 f
    float* ed1  = es1 + 960000;                              // 960,000 f
    float* agg1 = ed1 + 960000;                              // 3,840,000 f
    float* ht2  = agg1 + 3840000;                            // 1,920,000 f
    float* es2  = ht2 + 1920000;                             // 60,000 f
    float* ed2  = es2 + 60000;                               // 60,000 f
    int* deg0     = (int*)(ed2 + 60000);                     // 15000
    int* off0     = deg0 + ND0;
    int* cur0     = off0 + ND0;
    int* deg1     = cur0 + ND0;
    int* off1     = deg1 + ND1;
    int* cur1     = off1 + ND1;
    int* srcsort0 = cur1 + ND1;                              // 360000
    int* srcsort1 = srcsort0 + NE0;                          // 180000
    // total ~49.2 MB

    kz_zero<<<(ND0 + 255)/256, 256, 0, stream>>>(deg0, deg1);
    kh_hist<<<(NE0 + NE1 + 255)/256, 256, 0, stream>>>(edst0, edst1, deg0, deg1);
    ks_scan<<<2, 1024, 0, stream>>>(deg0, off0, cur0, deg1, off1, cur1);
    kc_scatter<<<(NE0 + NE1 + 255)/256, 256, 0, stream>>>(esrc0, edst0, esrc1, edst1,
                                                          cur0, cur1, srcsort0, srcsort1);
    k1_node1<<<(NB*NS0)/64, 256, 0, stream>>>(x, n_id0, W1, a_src1, a_dst1, ht1b, es1, ed1);
    k3_agg1<<<NB*K3CH, 256, 0, stream>>>(srcsort0, off0, deg0, res0, es1, ed1, ht1b, b1, agg1);
    k5_node2<<<(NB*ND0 + 127)/128, 256, 0, stream>>>(agg1, W2, a_src2, a_dst2, ht2, es2, ed2);
    k7_agg2<<<NB*K7CH, 256, 0, stream>>>(srcsort1, off1, deg1, res1, es2, ed2, ht2, b2, outp);
}

// Round 11
// 252.608 us; speedup vs baseline: 1.0925x; 1.0925x over previous
//
#include <hip/hip_runtime.h>

#define NB 4
#define NT 40000
#define NS0 30000
#define ND0 15000
#define NE0 360000
#define ND1 7500
#define NE1 180000
#define NEG 0.2f

typedef __attribute__((ext_vector_type(8))) short bf8;
typedef __attribute__((ext_vector_type(4))) float f4;

__device__ __forceinline__ unsigned short f2bf(float f) {
    unsigned u = __float_as_uint(f);
    u += 0x7FFF + ((u >> 16) & 1);          // round-to-nearest-even
    return (unsigned short)(u >> 16);
}
// packed bf16 pair in a uint: low ushort = even channel, high = odd channel
__device__ __forceinline__ float bf_lo(unsigned u) { return __uint_as_float(u << 16); }
__device__ __forceinline__ float bf_hi(unsigned u) { return __uint_as_float(u & 0xFFFF0000u); }

// ---------------- histogram of edge destinations ---------------------------
// (deg0|deg1 zeroed by hipMemsetAsync before this launch)
__global__ void kh_hist(const int* __restrict__ edst0, const int* __restrict__ edst1,
                        int* __restrict__ deg0, int* __restrict__ deg1) {
    int t = blockIdx.x * blockDim.x + threadIdx.x;
    if (t < NE0) atomicAdd(&deg0[edst0[t]], 1);
    else if (t < NE0 + NE1) atomicAdd(&deg1[edst1[t - NE0]], 1);
}

// ---------------- exclusive scan (one block per layer) ---------------------
__device__ void scan_block(const int* __restrict__ deg, int* __restrict__ off,
                           int* __restrict__ cur, int n) {
    __shared__ int s[1024];
    int t = threadIdx.x;
    int chunk = (n + 1023) / 1024;
    int base = t * chunk;
    int mysum = 0;
    for (int i = 0; i < chunk; ++i) {
        int idx = base + i;
        if (idx < n) mysum += deg[idx];
    }
    s[t] = mysum;
    __syncthreads();
    for (int o = 1; o < 1024; o <<= 1) {
        int v = (t >= o) ? s[t - o] : 0;
        __syncthreads();
        s[t] += v;
        __syncthreads();
    }
    int run = s[t] - mysum;   // exclusive prefix of my chunk
    for (int i = 0; i < chunk; ++i) {
        int idx = base + i;
        if (idx < n) {
            off[idx] = run;
            cur[idx] = run;
            run += deg[idx];
        }
    }
}

__global__ void ks_scan(const int* __restrict__ deg0, int* __restrict__ off0, int* __restrict__ cur0,
                        const int* __restrict__ deg1, int* __restrict__ off1, int* __restrict__ cur1) {
    if (blockIdx.x == 0) scan_block(deg0, off0, cur0, ND0);
    else                 scan_block(deg1, off1, cur1, ND1);
}

// ---------------- scatter src ids into dst-sorted order --------------------
__global__ void kc_scatter(const int* __restrict__ esrc0, const int* __restrict__ edst0,
                           const int* __restrict__ esrc1, const int* __restrict__ edst1,
                           int* __restrict__ cur0, int* __restrict__ cur1,
                           int* __restrict__ srcsort0, int* __restrict__ srcsort1) {
    int t = blockIdx.x * blockDim.x + threadIdx.x;
    if (t < NE0) {
        int pos = atomicAdd(&cur0[edst0[t]], 1);
        srcsort0[pos] = esrc0[t];
    } else if (t < NE0 + NE1) {
        int e = t - NE0;
        int pos = atomicAdd(&cur1[edst1[e]], 1);
        srcsort1[pos] = esrc1[e];
    }
}

// ---------------- layer 1 node transform (MFMA bf16 GEMM) ------------------
__global__ __launch_bounds__(256) void k1_node1(
        const float* __restrict__ x, const int* __restrict__ n_id0,
        const float* __restrict__ W1, const float* __restrict__ a_src,
        const float* __restrict__ a_dst,
        unsigned short* __restrict__ ht1b, float* __restrict__ es1, float* __restrict__ ed1) {
    __shared__ unsigned short xtb[64*72];
    __shared__ unsigned short wtb[64*72];
    __shared__ float asl[64], adl[64];
    int t = threadIdx.x;
    {
        int k = t >> 2, nb = (t & 3) * 16;
        const float* wrow = &W1[k*64 + nb];
        #pragma unroll
        for (int j = 0; j < 16; j += 4) {
            float4 v = *(const float4*)&wrow[j];
            wtb[(nb+j+0)*72 + k] = f2bf(v.x);
            wtb[(nb+j+1)*72 + k] = f2bf(v.y);
            wtb[(nb+j+2)*72 + k] = f2bf(v.z);
            wtb[(nb+j+3)*72 + k] = f2bf(v.w);
        }
    }
    if (t < 64) { asl[t] = a_src[t]; adl[t] = a_dst[t]; }
    {
        int rr = t & 63;
        int q4 = t >> 6;
        int row_s = blockIdx.x * 64 + rr;           // < 120000 (1875*64)
        int bs = row_s / NS0;
        int ns = row_s - bs * NS0;
        const float* xrow = x + ((size_t)(bs * NT + n_id0[ns])) * 64;
        #pragma unroll
        for (int j = 0; j < 4; ++j) {
            int k = q4 * 16 + j * 4;
            float4 v = *(const float4*)&xrow[k];
            ushort4 u;
            u.x = f2bf(v.x); u.y = f2bf(v.y); u.z = f2bf(v.z); u.w = f2bf(v.w);
            *(ushort4*)&xtb[rr*72 + k] = u;
        }
    }
    __syncthreads();
    int w = t >> 6, lane = t & 63, quad = lane >> 4, cl = lane & 15;
    int arow = 16*w + cl;
    bf8 a0 = *(const bf8*)&xtb[arow*72 + quad*8];        // A[m=cl][k=quad*8+j]
    bf8 a1 = *(const bf8*)&xtb[arow*72 + 32 + quad*8];   // k+32
    f4 acc[4];
    #pragma unroll
    for (int sub = 0; sub < 4; ++sub) {
        int n = sub*16 + cl;
        bf8 b0 = *(const bf8*)&wtb[n*72 + quad*8];       // B[k][n=cl]
        bf8 b1 = *(const bf8*)&wtb[n*72 + 32 + quad*8];
        f4 c = {0.f, 0.f, 0.f, 0.f};
        c = __builtin_amdgcn_mfma_f32_16x16x32_bf16(a0, b0, c, 0, 0, 0);
        c = __builtin_amdgcn_mfma_f32_16x16x32_bf16(a1, b1, c, 0, 0, 0);
        acc[sub] = c;
    }
    int rbase = blockIdx.x*64 + 16*w + quad*4;
    #pragma unroll
    for (int sub = 0; sub < 4; ++sub)
        #pragma unroll
        for (int r = 0; r < 4; ++r)
            ht1b[(size_t)(rbase + r)*64 + sub*16 + cl] = f2bf(acc[sub][r]);
    #pragma unroll
    for (int r = 0; r < 4; ++r) {
        #pragma unroll
        for (int sub = 0; sub < 4; ++sub) {
            int col = sub*16 + cl;
            float ps = acc[sub][r] * asl[col];
            float pd = acc[sub][r] * adl[col];
            ps += __shfl_xor(ps, 1); ps += __shfl_xor(ps, 2); ps += __shfl_xor(ps, 4);
            pd += __shfl_xor(pd, 1); pd += __shfl_xor(pd, 2); pd += __shfl_xor(pd, 4);
            if ((cl & 7) == 0) {
                int h = sub*2 + (cl >> 3);
                es1[(rbase + r)*8 + h] = ps;
                ed1[(rbase + r)*8 + h] = pd;
            }
        }
    }
}

// ---------------- layer 1 per-dst aggregation (R9 structure, best measured)-
// batch-major blocks (4 dsts x 1 batch). Wave: 8 x 8-lane edge groups,
// lane = 1 head = 8 channels (uint4 16B bf16), 2-deep unroll + index
// prefetch. One dst per wave -> 60000 waves = TLP hides gather latency.
__global__ __launch_bounds__(256) void k3_agg1(
        const int* __restrict__ srcsort0, const int* __restrict__ off0,
        const int* __restrict__ deg0, const int* __restrict__ res0,
        const float* __restrict__ es1, const float* __restrict__ ed1,
        const unsigned short* __restrict__ ht1b, const float* __restrict__ b1,
        float* __restrict__ agg1) {
    int b = blockIdx.x / (ND0/4);
    int chunk = blockIdx.x - b * (ND0/4);
    int d = chunk * 4 + (threadIdx.x >> 6);
    int lane = threadIdx.x & 63;
    int grp = lane >> 3;                   // edge slot 0..7
    int c = lane & 7;                      // head index; channels 8c..8c+7
    int dn = res0[d];
    float edv = ed1[(b*NS0 + dn)*8 + c];
    int start = off0[d];
    int cnt = deg0[d];
    float acc[8] = {};
    float wsum = 0.f;
    int i = grp;
    int sA = (i < cnt) ? srcsort0[start + i] : 0;
    int sB = (i + 8 < cnt) ? srcsort0[start + i + 8] : 0;
    while (i + 8 < cnt) {
        int inx = i + 16;
        int pA = (inx < cnt) ? srcsort0[start + inx] : 0;
        int pB = (inx + 8 < cnt) ? srcsort0[start + inx + 8] : 0;
        float e0 = es1[(b*NS0 + sA)*8 + c] + edv;
        float e1 = es1[(b*NS0 + sB)*8 + c] + edv;
        uint4 h0 = *(const uint4*)&ht1b[((size_t)(b*NS0 + sA))*64 + c*8];
        uint4 h1 = *(const uint4*)&ht1b[((size_t)(b*NS0 + sB))*64 + c*8];
        e0 = e0 > 0.f ? e0 : NEG * e0;
        e1 = e1 > 0.f ? e1 : NEG * e1;
        float w0 = __expf(e0), w1 = __expf(e1);
        acc[0] = fmaf(w0, bf_lo(h0.x), acc[0]); acc[1] = fmaf(w0, bf_hi(h0.x), acc[1]);
        acc[2] = fmaf(w0, bf_lo(h0.y), acc[2]); acc[3] = fmaf(w0, bf_hi(h0.y), acc[3]);
        acc[4] = fmaf(w0, bf_lo(h0.z), acc[4]); acc[5] = fmaf(w0, bf_hi(h0.z), acc[5]);
        acc[6] = fmaf(w0, bf_lo(h0.w), acc[6]); acc[7] = fmaf(w0, bf_hi(h0.w), acc[7]);
        acc[0] = fmaf(w1, bf_lo(h1.x), acc[0]); acc[1] = fmaf(w1, bf_hi(h1.x), acc[1]);
        acc[2] = fmaf(w1, bf_lo(h1.y), acc[2]); acc[3] = fmaf(w1, bf_hi(h1.y), acc[3]);
        acc[4] = fmaf(w1, bf_lo(h1.z), acc[4]); acc[5] = fmaf(w1, bf_hi(h1.z), acc[5]);
        acc[6] = fmaf(w1, bf_lo(h1.w), acc[6]); acc[7] = fmaf(w1, bf_hi(h1.w), acc[7]);
        wsum += w0 + w1;
        sA = pA; sB = pB; i = inx;
    }
    if (i < cnt) {   // at most one edge left in this slot; sA is valid
        float e0 = es1[(b*NS0 + sA)*8 + c] + edv;
        uint4 h0 = *(const uint4*)&ht1b[((size_t)(b*NS0 + sA))*64 + c*8];
        e0 = e0 > 0.f ? e0 : NEG * e0;
        float w0 = __expf(e0);
        acc[0] = fmaf(w0, bf_lo(h0.x), acc[0]); acc[1] = fmaf(w0, bf_hi(h0.x), acc[1]);
        acc[2] = fmaf(w0, bf_lo(h0.y), acc[2]); acc[3] = fmaf(w0, bf_hi(h0.y), acc[3]);
        acc[4] = fmaf(w0, bf_lo(h0.z), acc[4]); acc[5] = fmaf(w0, bf_hi(h0.z), acc[5]);
        acc[6] = fmaf(w0, bf_lo(h0.w), acc[6]); acc[7] = fmaf(w0, bf_hi(h0.w), acc[7]);
        wsum += w0;
    }
    #pragma unroll
    for (int j = 0; j < 8; ++j) {
        acc[j] += __shfl_xor(acc[j], 8);
        acc[j] += __shfl_xor(acc[j], 16);
        acc[j] += __shfl_xor(acc[j], 32);
    }
    wsum += __shfl_xor(wsum, 8); wsum += __shfl_xor(wsum, 16); wsum += __shfl_xor(wsum, 32);
    if (grp == 0) {
        float inv = cnt > 0 ? 1.f / wsum : 0.f;
        float4 b_lo = *(const float4*)&b1[c*8];
        float4 b_hi = *(const float4*)&b1[c*8 + 4];
        float o[8];
        o[0] = acc[0]*inv + b_lo.x; o[1] = acc[1]*inv + b_lo.y;
        o[2] = acc[2]*inv + b_lo.z; o[3] = acc[3]*inv + b_lo.w;
        o[4] = acc[4]*inv + b_hi.x; o[5] = acc[5]*inv + b_hi.y;
        o[6] = acc[6]*inv + b_hi.z; o[7] = acc[7]*inv + b_hi.w;
        #pragma unroll
        for (int j = 0; j < 8; ++j) o[j] = o[j] > 0.f ? o[j] : __expf(o[j]) - 1.f;
        float* orow = &agg1[((size_t)(b*ND0 + d))*64 + c*8];
        *(float4*)&orow[0] = make_float4(o[0], o[1], o[2], o[3]);
        *(float4*)&orow[4] = make_float4(o[4], o[5], o[6], o[7]);
    }
}

// ---------------- layer 2 node transform (register-blocked GEMM) -----------
__global__ __launch_bounds__(256) void k5_node2(
        const float* __restrict__ h, const float* __restrict__ W2,
        const float* __restrict__ a_src2, const float* __restrict__ a_dst2,
        float* __restrict__ ht2, float* __restrict__ es2, float* __restrict__ ed2) {
    __shared__ float xt[64*132];
    __shared__ float Wl[64*32];
    __shared__ float as2[32], ad2[32];
    int t = threadIdx.x;
    for (int i = t; i < 512; i += 256)
        *(float4*)&Wl[i*4] = *(const float4*)&W2[i*4];
    if (t < 32) { as2[t] = a_src2[t]; ad2[t] = a_dst2[t]; }
    int rr = t & 127;
    int q  = t >> 7;
    int row_s = blockIdx.x * 128 + rr;
    bool valid = row_s < NB*ND0;
    const float* hrow = h + (size_t)row_s * 64;
    #pragma unroll
    for (int j = 0; j < 8; ++j) {
        int k = q * 32 + j * 4;
        float4 v = valid ? *(const float4*)&hrow[k] : make_float4(0.f,0.f,0.f,0.f);
        xt[(k+0)*132 + rr] = v.x;
        xt[(k+1)*132 + rr] = v.y;
        xt[(k+2)*132 + rr] = v.z;
        xt[(k+3)*132 + rr] = v.w;
    }
    __syncthreads();
    int c0 = (t & 7) * 4;
    int r0 = (t >> 3) * 4;
    float acc[4][4] = {};
    #pragma unroll 16
    for (int k = 0; k < 64; ++k) {
        float4 a = *(const float4*)&xt[k*132 + r0];
        float4 w = *(const float4*)&Wl[k*32 + c0];
        acc[0][0] = fmaf(a.x, w.x, acc[0][0]); acc[0][1] = fmaf(a.x, w.y, acc[0][1]);
        acc[0][2] = fmaf(a.x, w.z, acc[0][2]); acc[0][3] = fmaf(a.x, w.w, acc[0][3]);
        acc[1][0] = fmaf(a.y, w.x, acc[1][0]); acc[1][1] = fmaf(a.y, w.y, acc[1][1]);
        acc[1][2] = fmaf(a.y, w.z, acc[1][2]); acc[1][3] = fmaf(a.y, w.w, acc[1][3]);
        acc[2][0] = fmaf(a.z, w.x, acc[2][0]); acc[2][1] = fmaf(a.z, w.y, acc[2][1]);
        acc[2][2] = fmaf(a.z, w.z, acc[2][2]); acc[2][3] = fmaf(a.z, w.w, acc[2][3]);
        acc[3][0] = fmaf(a.w, w.x, acc[3][0]); acc[3][1] = fmaf(a.w, w.y, acc[3][1]);
        acc[3][2] = fmaf(a.w, w.z, acc[3][2]); acc[3][3] = fmaf(a.w, w.w, acc[3][3]);
    }
    float s0 = as2[c0], s1 = as2[c0+1], s2 = as2[c0+2], s3 = as2[c0+3];
    float d0 = ad2[c0], d1 = ad2[c0+1], d2 = ad2[c0+2], d3 = ad2[c0+3];
    #pragma unroll
    for (int i = 0; i < 4; ++i) {
        int row = blockIdx.x * 128 + r0 + i;
        float ps = acc[i][0]*s0 + acc[i][1]*s1 + acc[i][2]*s2 + acc[i][3]*s3;
        float pd = acc[i][0]*d0 + acc[i][1]*d1 + acc[i][2]*d2 + acc[i][3]*d3;
        ps += __shfl_xor(ps, 1); ps += __shfl_xor(ps, 2); ps += __shfl_xor(ps, 4);
        pd += __shfl_xor(pd, 1); pd += __shfl_xor(pd, 2); pd += __shfl_xor(pd, 4);
        if (row < NB*ND0) {
            *(float4*)&ht2[(size_t)row*32 + c0] =
                make_float4(acc[i][0], acc[i][1], acc[i][2], acc[i][3]);
            if ((t & 7) == 0) { es2[row] = ps; ed2[row] = pd; }
        }
    }
}

// ---------------- layer 2 per-dst aggregation (R9 structure) ---------------
__global__ __launch_bounds__(256) void k7_agg2(
        const int* __restrict__ srcsort1, const int* __restrict__ off1,
        const int* __restrict__ deg1, const int* __restrict__ res1,
        const float* __restrict__ es2, const float* __restrict__ ed2,
        const float* __restrict__ ht2, const float* __restrict__ b2,
        float* __restrict__ outp) {
    int b = blockIdx.x / (ND1/4);
    int chunk = blockIdx.x - b * (ND1/4);
    int d = chunk * 4 + (threadIdx.x >> 6);
    int lane = threadIdx.x & 63;
    int grp = lane >> 3;                   // edge slot 0..7
    int c = lane & 7;                      // channel quad: channels 4c..4c+3
    int dn = res1[d];
    float edv = ed2[b*ND0 + dn];
    int start = off1[d];
    int cnt = deg1[d];
    float ax = 0.f, ay = 0.f, az = 0.f, aw = 0.f, wsum = 0.f;
    int i = grp;
    int sA = (i < cnt) ? srcsort1[start + i] : 0;
    int sB = (i + 8 < cnt) ? srcsort1[start + i + 8] : 0;
    while (i + 8 < cnt) {
        int inx = i + 16;
        int pA = (inx < cnt) ? srcsort1[start + inx] : 0;
        int pB = (inx + 8 < cnt) ? srcsort1[start + inx + 8] : 0;
        float lg0 = es2[b*ND0 + sA] + edv;
        float lg1 = es2[b*ND0 + sB] + edv;
        float4 h0 = *(const float4*)&ht2[((size_t)(b*ND0 + sA))*32 + c*4];
        float4 h1 = *(const float4*)&ht2[((size_t)(b*ND0 + sB))*32 + c*4];
        lg0 = lg0 > 0.f ? lg0 : NEG * lg0;
        lg1 = lg1 > 0.f ? lg1 : NEG * lg1;
        float w0 = __expf(lg0), w1 = __expf(lg1);
        ax = fmaf(w0, h0.x, ax); ay = fmaf(w0, h0.y, ay);
        az = fmaf(w0, h0.z, az); aw = fmaf(w0, h0.w, aw);
        ax = fmaf(w1, h1.x, ax); ay = fmaf(w1, h1.y, ay);
        az = fmaf(w1, h1.z, az); aw = fmaf(w1, h1.w, aw);
        wsum += w0 + w1;
        sA = pA; sB = pB; i = inx;
    }
    if (i < cnt) {
        float lg0 = es2[b*ND0 + sA] + edv;
        float4 h0 = *(const float4*)&ht2[((size_t)(b*ND0 + sA))*32 + c*4];
        lg0 = lg0 > 0.f ? lg0 : NEG * lg0;
        float w0 = __expf(lg0);
        ax = fmaf(w0, h0.x, ax); ay = fmaf(w0, h0.y, ay);
        az = fmaf(w0, h0.z, az); aw = fmaf(w0, h0.w, aw);
        wsum += w0;
    }
    ax += __shfl_xor(ax, 8); ax += __shfl_xor(ax, 16); ax += __shfl_xor(ax, 32);
    ay += __shfl_xor(ay, 8); ay += __shfl_xor(ay, 16); ay += __shfl_xor(ay, 32);
    az += __shfl_xor(az, 8); az += __shfl_xor(az, 16); az += __shfl_xor(az, 32);
    aw += __shfl_xor(aw, 8); aw += __shfl_xor(aw, 16); aw += __shfl_xor(aw, 32);
    wsum += __shfl_xor(wsum, 8); wsum += __shfl_xor(wsum, 16); wsum += __shfl_xor(wsum, 32);
    if (grp == 0) {
        float inv = cnt > 0 ? 1.f / wsum : 0.f;
        float4 bb = *(const float4*)&b2[c*4];
        float4 o;
        o.x = ax*inv + bb.x; o.y = ay*inv + bb.y;
        o.z = az*inv + bb.z; o.w = aw*inv + bb.w;
        *(float4*)&outp[((size_t)(b*ND1 + d))*32 + c*4] = o;
    }
}

extern "C" void kernel_launch(void* const* d_in, const int* in_sizes, int n_in,
                              void* d_out, int out_size, void* d_ws, size_t ws_size,
                              hipStream_t stream) {
    const float* x        = (const float*)d_in[0];
    const int*   n_id0    = (const int*)d_in[1];
    const int*   res0     = (const int*)d_in[2];
    const int*   esrc0    = (const int*)d_in[3];
    const int*   edst0    = (const int*)d_in[4];
    const int*   res1     = (const int*)d_in[5];
    const int*   esrc1    = (const int*)d_in[6];
    const int*   edst1    = (const int*)d_in[7];
    const float* W1       = (const float*)d_in[8];
    const float* a_src1   = (const float*)d_in[9];
    const float* a_dst1   = (const float*)d_in[10];
    const float* b1       = (const float*)d_in[11];
    const float* W2       = (const float*)d_in[12];
    const float* a_src2   = (const float*)d_in[13];
    const float* a_dst2   = (const float*)d_in[14];
    const float* b2       = (const float*)d_in[15];
    float* outp = (float*)d_out;

    char* base = (char*)d_ws;
    unsigned short* ht1b = (unsigned short*)base;            // 120000*64*2  = 15,360,000 B
    float* es1  = (float*)(base + 15360000);                 // 960,000 f
    float* ed1  = es1 + 960000;                              // 960,000 f
    float* agg1 = ed1 + 960000;                              // 3,840,000 f
    float* ht2  = agg1 + 3840000;                            // 1,920,000 f
    float* es2  = ht2 + 1920000;                             // 60,000 f
    float* ed2  = es2 + 60000;                               // 60,000 f
    // deg0|deg1 contiguous so one memsetAsync zeroes both
    int* deg0     = (int*)(ed2 + 60000);                     // 15000
    int* deg1     = deg0 + ND0;                              // 7500
    int* off0     = deg1 + ND1;                              // 15000
    int* cur0     = off0 + ND0;                              // 15000
    int* off1     = cur0 + ND0;                              // 7500
    int* cur1     = off1 + ND1;                              // 7500
    int* srcsort0 = cur1 + ND1;                              // 360000
    int* srcsort1 = srcsort0 + NE0;                          // 180000
    // total ~49.2 MB

    hipMemsetAsync(deg0, 0, (ND0 + ND1) * sizeof(int), stream);
    kh_hist<<<(NE0 + NE1 + 255)/256, 256, 0, stream>>>(edst0, edst1, deg0, deg1);
    ks_scan<<<2, 1024, 0, stream>>>(deg0, off0, cur0, deg1, off1, cur1);
    kc_scatter<<<(NE0 + NE1 + 255)/256, 256, 0, stream>>>(esrc0, edst0, esrc1, edst1,
                                                          cur0, cur1, srcsort0, srcsort1);
    k1_node1<<<(NB*NS0)/64, 256, 0, stream>>>(x, n_id0, W1, a_src1, a_dst1, ht1b, es1, ed1);
    k3_agg1<<<NB*(ND0/4), 256, 0, stream>>>(srcsort0, off0, deg0, res0, es1, ed1, ht1b, b1, agg1);
    k5_node2<<<(NB*ND0 + 127)/128, 256, 0, stream>>>(agg1, W2, a_src2, a_dst2, ht2, es2, ed2);
    k7_agg2<<<NB*(ND1/4), 256, 0, stream>>>(srcsort1, off1, deg1, res1, es2, ed2, ht2, b2, outp);
}

// Round 12
// 245.102 us; speedup vs baseline: 1.1259x; 1.0306x over previous
//
#include <hip/hip_runtime.h>

#define NB 4
#define NT 40000
#define NS0 30000
#define ND0 15000
#define NE0 360000
#define ND1 7500
#define NE1 180000
#define NEG 0.2f

#define K1B ((NB*NS0)/64)                 // 1875 GEMM blocks
#define HB  ((NE0 + NE1 + 255)/256)       // 2110 histogram blocks

typedef __attribute__((ext_vector_type(8))) short bf8;
typedef __attribute__((ext_vector_type(4))) float f4;

__device__ __forceinline__ unsigned short f2bf(float f) {
    unsigned u = __float_as_uint(f);
    u += 0x7FFF + ((u >> 16) & 1);          // round-to-nearest-even
    return (unsigned short)(u >> 16);
}
// packed bf16 pair in a uint: low ushort = even channel, high = odd channel
__device__ __forceinline__ float bf_lo(unsigned u) { return __uint_as_float(u << 16); }
__device__ __forceinline__ float bf_hi(unsigned u) { return __uint_as_float(u & 0xFFFF0000u); }

// ---------------- fused: layer-1 MFMA GEMM + edge histograms ---------------
// blocks [0, K1B): node transform; blocks [K1B, K1B+HB): histogram.
// The two jobs are independent; fusing overlaps GEMM (MFMA/LDS-bound) with
// the histogram (memory/atomic-bound) instead of serializing them.
__global__ __launch_bounds__(256) void kA_gemm_hist(
        const float* __restrict__ x, const int* __restrict__ n_id0,
        const float* __restrict__ W1, const float* __restrict__ a_src,
        const float* __restrict__ a_dst,
        unsigned short* __restrict__ ht1b, float* __restrict__ es1, float* __restrict__ ed1,
        const int* __restrict__ edst0, const int* __restrict__ edst1,
        int* __restrict__ deg0, int* __restrict__ deg1) {
    __shared__ unsigned short xtb[64*72];
    __shared__ unsigned short wtb[64*72];
    __shared__ float asl[64], adl[64];
    if (blockIdx.x >= K1B) {                 // ---- histogram part ----
        int t = (blockIdx.x - K1B) * 256 + threadIdx.x;
        if (t < NE0) atomicAdd(&deg0[edst0[t]], 1);
        else if (t < NE0 + NE1) atomicAdd(&deg1[edst1[t - NE0]], 1);
        return;
    }
    // ---- GEMM part (identical to R11 k1_node1) ----
    int t = threadIdx.x;
    {
        int k = t >> 2, nb = (t & 3) * 16;
        const float* wrow = &W1[k*64 + nb];
        #pragma unroll
        for (int j = 0; j < 16; j += 4) {
            float4 v = *(const float4*)&wrow[j];
            wtb[(nb+j+0)*72 + k] = f2bf(v.x);
            wtb[(nb+j+1)*72 + k] = f2bf(v.y);
            wtb[(nb+j+2)*72 + k] = f2bf(v.z);
            wtb[(nb+j+3)*72 + k] = f2bf(v.w);
        }
    }
    if (t < 64) { asl[t] = a_src[t]; adl[t] = a_dst[t]; }
    {
        int rr = t & 63;
        int q4 = t >> 6;
        int row_s = blockIdx.x * 64 + rr;           // < 120000 (1875*64)
        int bs = row_s / NS0;
        int ns = row_s - bs * NS0;
        const float* xrow = x + ((size_t)(bs * NT + n_id0[ns])) * 64;
        #pragma unroll
        for (int j = 0; j < 4; ++j) {
            int k = q4 * 16 + j * 4;
            float4 v = *(const float4*)&xrow[k];
            ushort4 u;
            u.x = f2bf(v.x); u.y = f2bf(v.y); u.z = f2bf(v.z); u.w = f2bf(v.w);
            *(ushort4*)&xtb[rr*72 + k] = u;
        }
    }
    __syncthreads();
    int w = t >> 6, lane = t & 63, quad = lane >> 4, cl = lane & 15;
    int arow = 16*w + cl;
    bf8 a0 = *(const bf8*)&xtb[arow*72 + quad*8];        // A[m=cl][k=quad*8+j]
    bf8 a1 = *(const bf8*)&xtb[arow*72 + 32 + quad*8];   // k+32
    f4 acc[4];
    #pragma unroll
    for (int sub = 0; sub < 4; ++sub) {
        int n = sub*16 + cl;
        bf8 b0 = *(const bf8*)&wtb[n*72 + quad*8];       // B[k][n=cl]
        bf8 b1 = *(const bf8*)&wtb[n*72 + 32 + quad*8];
        f4 c = {0.f, 0.f, 0.f, 0.f};
        c = __builtin_amdgcn_mfma_f32_16x16x32_bf16(a0, b0, c, 0, 0, 0);
        c = __builtin_amdgcn_mfma_f32_16x16x32_bf16(a1, b1, c, 0, 0, 0);
        acc[sub] = c;
    }
    int rbase = blockIdx.x*64 + 16*w + quad*4;
    #pragma unroll
    for (int sub = 0; sub < 4; ++sub)
        #pragma unroll
        for (int r = 0; r < 4; ++r)
            ht1b[(size_t)(rbase + r)*64 + sub*16 + cl] = f2bf(acc[sub][r]);
    #pragma unroll
    for (int r = 0; r < 4; ++r) {
        #pragma unroll
        for (int sub = 0; sub < 4; ++sub) {
            int col = sub*16 + cl;
            float ps = acc[sub][r] * asl[col];
            float pd = acc[sub][r] * adl[col];
            ps += __shfl_xor(ps, 1); ps += __shfl_xor(ps, 2); ps += __shfl_xor(ps, 4);
            pd += __shfl_xor(pd, 1); pd += __shfl_xor(pd, 2); pd += __shfl_xor(pd, 4);
            if ((cl & 7) == 0) {
                int h = sub*2 + (cl >> 3);
                es1[(rbase + r)*8 + h] = ps;
                ed1[(rbase + r)*8 + h] = pd;
            }
        }
    }
}

// ---------------- exclusive scan (one block per layer) ---------------------
__device__ void scan_block(const int* __restrict__ deg, int* __restrict__ off,
                           int* __restrict__ cur, int n) {
    __shared__ int s[1024];
    int t = threadIdx.x;
    int chunk = (n + 1023) / 1024;
    int base = t * chunk;
    int mysum = 0;
    for (int i = 0; i < chunk; ++i) {
        int idx = base + i;
        if (idx < n) mysum += deg[idx];
    }
    s[t] = mysum;
    __syncthreads();
    for (int o = 1; o < 1024; o <<= 1) {
        int v = (t >= o) ? s[t - o] : 0;
        __syncthreads();
        s[t] += v;
        __syncthreads();
    }
    int run = s[t] - mysum;   // exclusive prefix of my chunk
    for (int i = 0; i < chunk; ++i) {
        int idx = base + i;
        if (idx < n) {
            off[idx] = run;
            cur[idx] = run;
            run += deg[idx];
        }
    }
}

__global__ void ks_scan(const int* __restrict__ deg0, int* __restrict__ off0, int* __restrict__ cur0,
                        const int* __restrict__ deg1, int* __restrict__ off1, int* __restrict__ cur1) {
    if (blockIdx.x == 0) scan_block(deg0, off0, cur0, ND0);
    else                 scan_block(deg1, off1, cur1, ND1);
}

// ---------------- scatter src ids into dst-sorted order --------------------
__global__ void kc_scatter(const int* __restrict__ esrc0, const int* __restrict__ edst0,
                           const int* __restrict__ esrc1, const int* __restrict__ edst1,
                           int* __restrict__ cur0, int* __restrict__ cur1,
                           int* __restrict__ srcsort0, int* __restrict__ srcsort1) {
    int t = blockIdx.x * blockDim.x + threadIdx.x;
    if (t < NE0) {
        int pos = atomicAdd(&cur0[edst0[t]], 1);
        srcsort0[pos] = esrc0[t];
    } else if (t < NE0 + NE1) {
        int e = t - NE0;
        int pos = atomicAdd(&cur1[edst1[e]], 1);
        srcsort1[pos] = esrc1[e];
    }
}

// ---------------- layer 1 per-dst aggregation ------------------------------
// R9 wave mapping (proven best: 1 dst/wave, 8 x 8-lane edge slots, batch-
// major blocks) + 4-deep branch-free pipeline: invalid slots clamp to src 0
// (L1-hot garbage row) with weight forced to 0 -> 12 independent loads in
// flight per lane, straight-line for deg <= 32.
__global__ __launch_bounds__(256) void k3_agg1(
        const int* __restrict__ srcsort0, const int* __restrict__ off0,
        const int* __restrict__ deg0, const int* __restrict__ res0,
        const float* __restrict__ es1, const float* __restrict__ ed1,
        const unsigned short* __restrict__ ht1b, const float* __restrict__ b1,
        float* __restrict__ agg1) {
    int b = blockIdx.x / (ND0/4);
    int chunk = blockIdx.x - b * (ND0/4);
    int d = chunk * 4 + (threadIdx.x >> 6);
    int lane = threadIdx.x & 63;
    int grp = lane >> 3;                   // edge slot 0..7
    int c = lane & 7;                      // head index; channels 8c..8c+7
    int dn = res0[d];
    float edv = ed1[(b*NS0 + dn)*8 + c];
    int start = off0[d];
    int cnt = deg0[d];
    const float* esb = es1 + (size_t)b*NS0*8;
    const unsigned short* htb = ht1b + (size_t)b*NS0*64;
    float acc[8] = {};
    float wsum = 0.f;
    int i = grp;
    bool v0 = i      < cnt, v1 = i + 8  < cnt,
         v2 = i + 16 < cnt, v3 = i + 24 < cnt;
    int s0 = v0 ? srcsort0[start + i]      : 0;
    int s1 = v1 ? srcsort0[start + i + 8]  : 0;
    int s2 = v2 ? srcsort0[start + i + 16] : 0;
    int s3 = v3 ? srcsort0[start + i + 24] : 0;
    for (;;) {
        float e0 = esb[s0*8 + c], e1 = esb[s1*8 + c];
        float e2 = esb[s2*8 + c], e3 = esb[s3*8 + c];
        uint4 h0 = *(const uint4*)&htb[(size_t)s0*64 + c*8];
        uint4 h1 = *(const uint4*)&htb[(size_t)s1*64 + c*8];
        uint4 h2 = *(const uint4*)&htb[(size_t)s2*64 + c*8];
        uint4 h3 = *(const uint4*)&htb[(size_t)s3*64 + c*8];
        int ni = i + 32;
        bool nv0 = ni      < cnt, nv1 = ni + 8  < cnt,
             nv2 = ni + 16 < cnt, nv3 = ni + 24 < cnt;
        int t0 = nv0 ? srcsort0[start + ni]      : 0;
        int t1 = nv1 ? srcsort0[start + ni + 8]  : 0;
        int t2 = nv2 ? srcsort0[start + ni + 16] : 0;
        int t3 = nv3 ? srcsort0[start + ni + 24] : 0;
        e0 += edv; e1 += edv; e2 += edv; e3 += edv;
        e0 = e0 > 0.f ? e0 : NEG * e0;
        e1 = e1 > 0.f ? e1 : NEG * e1;
        e2 = e2 > 0.f ? e2 : NEG * e2;
        e3 = e3 > 0.f ? e3 : NEG * e3;
        float w0 = v0 ? __expf(e0) : 0.f;
        float w1 = v1 ? __expf(e1) : 0.f;
        float w2 = v2 ? __expf(e2) : 0.f;
        float w3 = v3 ? __expf(e3) : 0.f;
        acc[0] = fmaf(w0, bf_lo(h0.x), acc[0]); acc[1] = fmaf(w0, bf_hi(h0.x), acc[1]);
        acc[2] = fmaf(w0, bf_lo(h0.y), acc[2]); acc[3] = fmaf(w0, bf_hi(h0.y), acc[3]);
        acc[4] = fmaf(w0, bf_lo(h0.z), acc[4]); acc[5] = fmaf(w0, bf_hi(h0.z), acc[5]);
        acc[6] = fmaf(w0, bf_lo(h0.w), acc[6]); acc[7] = fmaf(w0, bf_hi(h0.w), acc[7]);
        acc[0] = fmaf(w1, bf_lo(h1.x), acc[0]); acc[1] = fmaf(w1, bf_hi(h1.x), acc[1]);
        acc[2] = fmaf(w1, bf_lo(h1.y), acc[2]); acc[3] = fmaf(w1, bf_hi(h1.y), acc[3]);
        acc[4] = fmaf(w1, bf_lo(h1.z), acc[4]); acc[5] = fmaf(w1, bf_hi(h1.z), acc[5]);
        acc[6] = fmaf(w1, bf_lo(h1.w), acc[6]); acc[7] = fmaf(w1, bf_hi(h1.w), acc[7]);
        acc[0] = fmaf(w2, bf_lo(h2.x), acc[0]); acc[1] = fmaf(w2, bf_hi(h2.x), acc[1]);
        acc[2] = fmaf(w2, bf_lo(h2.y), acc[2]); acc[3] = fmaf(w2, bf_hi(h2.y), acc[3]);
        acc[4] = fmaf(w2, bf_lo(h2.z), acc[4]); acc[5] = fmaf(w2, bf_hi(h2.z), acc[5]);
        acc[6] = fmaf(w2, bf_lo(h2.w), acc[6]); acc[7] = fmaf(w2, bf_hi(h2.w), acc[7]);
        acc[0] = fmaf(w3, bf_lo(h3.x), acc[0]); acc[1] = fmaf(w3, bf_hi(h3.x), acc[1]);
        acc[2] = fmaf(w3, bf_lo(h3.y), acc[2]); acc[3] = fmaf(w3, bf_hi(h3.y), acc[3]);
        acc[4] = fmaf(w3, bf_lo(h3.z), acc[4]); acc[5] = fmaf(w3, bf_hi(h3.z), acc[5]);
        acc[6] = fmaf(w3, bf_lo(h3.w), acc[6]); acc[7] = fmaf(w3, bf_hi(h3.w), acc[7]);
        wsum += (w0 + w1) + (w2 + w3);
        i = ni; s0 = t0; s1 = t1; s2 = t2; s3 = t3;
        v0 = nv0; v1 = nv1; v2 = nv2; v3 = nv3;
        if (i >= cnt) break;
    }
    #pragma unroll
    for (int j = 0; j < 8; ++j) {
        acc[j] += __shfl_xor(acc[j], 8);
        acc[j] += __shfl_xor(acc[j], 16);
        acc[j] += __shfl_xor(acc[j], 32);
    }
    wsum += __shfl_xor(wsum, 8); wsum += __shfl_xor(wsum, 16); wsum += __shfl_xor(wsum, 32);
    if (grp == 0) {
        float inv = cnt > 0 ? 1.f / wsum : 0.f;
        float4 b_lo = *(const float4*)&b1[c*8];
        float4 b_hi = *(const float4*)&b1[c*8 + 4];
        float o[8];
        o[0] = acc[0]*inv + b_lo.x; o[1] = acc[1]*inv + b_lo.y;
        o[2] = acc[2]*inv + b_lo.z; o[3] = acc[3]*inv + b_lo.w;
        o[4] = acc[4]*inv + b_hi.x; o[5] = acc[5]*inv + b_hi.y;
        o[6] = acc[6]*inv + b_hi.z; o[7] = acc[7]*inv + b_hi.w;
        #pragma unroll
        for (int j = 0; j < 8; ++j) o[j] = o[j] > 0.f ? o[j] : __expf(o[j]) - 1.f;
        float* orow = &agg1[((size_t)(b*ND0 + d))*64 + c*8];
        *(float4*)&orow[0] = make_float4(o[0], o[1], o[2], o[3]);
        *(float4*)&orow[4] = make_float4(o[4], o[5], o[6], o[7]);
    }
}

// ---------------- layer 2 node transform (register-blocked GEMM) -----------
__global__ __launch_bounds__(256) void k5_node2(
        const float* __restrict__ h, const float* __restrict__ W2,
        const float* __restrict__ a_src2, const float* __restrict__ a_dst2,
        float* __restrict__ ht2, float* __restrict__ es2, float* __restrict__ ed2) {
    __shared__ float xt[64*132];
    __shared__ float Wl[64*32];
    __shared__ float as2[32], ad2[32];
    int t = threadIdx.x;
    for (int i = t; i < 512; i += 256)
        *(float4*)&Wl[i*4] = *(const float4*)&W2[i*4];
    if (t < 32) { as2[t] = a_src2[t]; ad2[t] = a_dst2[t]; }
    int rr = t & 127;
    int q  = t >> 7;
    int row_s = blockIdx.x * 128 + rr;
    bool valid = row_s < NB*ND0;
    const float* hrow = h + (size_t)row_s * 64;
    #pragma unroll
    for (int j = 0; j < 8; ++j) {
        int k = q * 32 + j * 4;
        float4 v = valid ? *(const float4*)&hrow[k] : make_float4(0.f,0.f,0.f,0.f);
        xt[(k+0)*132 + rr] = v.x;
        xt[(k+1)*132 + rr] = v.y;
        xt[(k+2)*132 + rr] = v.z;
        xt[(k+3)*132 + rr] = v.w;
    }
    __syncthreads();
    int c0 = (t & 7) * 4;
    int r0 = (t >> 3) * 4;
    float acc[4][4] = {};
    #pragma unroll 16
    for (int k = 0; k < 64; ++k) {
        float4 a = *(const float4*)&xt[k*132 + r0];
        float4 w = *(const float4*)&Wl[k*32 + c0];
        acc[0][0] = fmaf(a.x, w.x, acc[0][0]); acc[0][1] = fmaf(a.x, w.y, acc[0][1]);
        acc[0][2] = fmaf(a.x, w.z, acc[0][2]); acc[0][3] = fmaf(a.x, w.w, acc[0][3]);
        acc[1][0] = fmaf(a.y, w.x, acc[1][0]); acc[1][1] = fmaf(a.y, w.y, acc[1][1]);
        acc[1][2] = fmaf(a.y, w.z, acc[1][2]); acc[1][3] = fmaf(a.y, w.w, acc[1][3]);
        acc[2][0] = fmaf(a.z, w.x, acc[2][0]); acc[2][1] = fmaf(a.z, w.y, acc[2][1]);
        acc[2][2] = fmaf(a.z, w.z, acc[2][2]); acc[2][3] = fmaf(a.z, w.w, acc[2][3]);
        acc[3][0] = fmaf(a.w, w.x, acc[3][0]); acc[3][1] = fmaf(a.w, w.y, acc[3][1]);
        acc[3][2] = fmaf(a.w, w.z, acc[3][2]); acc[3][3] = fmaf(a.w, w.w, acc[3][3]);
    }
    float s0 = as2[c0], s1 = as2[c0+1], s2 = as2[c0+2], s3 = as2[c0+3];
    float d0 = ad2[c0], d1 = ad2[c0+1], d2 = ad2[c0+2], d3 = ad2[c0+3];
    #pragma unroll
    for (int i = 0; i < 4; ++i) {
        int row = blockIdx.x * 128 + r0 + i;
        float ps = acc[i][0]*s0 + acc[i][1]*s1 + acc[i][2]*s2 + acc[i][3]*s3;
        float pd = acc[i][0]*d0 + acc[i][1]*d1 + acc[i][2]*d2 + acc[i][3]*d3;
        ps += __shfl_xor(ps, 1); ps += __shfl_xor(ps, 2); ps += __shfl_xor(ps, 4);
        pd += __shfl_xor(pd, 1); pd += __shfl_xor(pd, 2); pd += __shfl_xor(pd, 4);
        if (row < NB*ND0) {
            *(float4*)&ht2[(size_t)row*32 + c0] =
                make_float4(acc[i][0], acc[i][1], acc[i][2], acc[i][3]);
            if ((t & 7) == 0) { es2[row] = ps; ed2[row] = pd; }
        }
    }
}

// ---------------- layer 2 per-dst aggregation (4-deep pipeline) ------------
__global__ __launch_bounds__(256) void k7_agg2(
        const int* __restrict__ srcsort1, const int* __restrict__ off1,
        const int* __restrict__ deg1, const int* __restrict__ res1,
        const float* __restrict__ es2, const float* __restrict__ ed2,
        const float* __restrict__ ht2, const float* __restrict__ b2,
        float* __restrict__ outp) {
    int b = blockIdx.x / (ND1/4);
    int chunk = blockIdx.x - b * (ND1/4);
    int d = chunk * 4 + (threadIdx.x >> 6);
    int lane = threadIdx.x & 63;
    int grp = lane >> 3;                   // edge slot 0..7
    int c = lane & 7;                      // channel quad: channels 4c..4c+3
    int dn = res1[d];
    float edv = ed2[b*ND0 + dn];
    int start = off1[d];
    int cnt = deg1[d];
    const float* esb = es2 + (size_t)b*ND0;
    const float* htb = ht2 + (size_t)b*ND0*32;
    float ax = 0.f, ay = 0.f, az = 0.f, aw = 0.f, wsum = 0.f;
    int i = grp;
    bool v0 = i      < cnt, v1 = i + 8  < cnt,
         v2 = i + 16 < cnt, v3 = i + 24 < cnt;
    int s0 = v0 ? srcsort1[start + i]      : 0;
    int s1 = v1 ? srcsort1[start + i + 8]  : 0;
    int s2 = v2 ? srcsort1[start + i + 16] : 0;
    int s3 = v3 ? srcsort1[start + i + 24] : 0;
    for (;;) {
        float lg0 = esb[s0], lg1 = esb[s1], lg2 = esb[s2], lg3 = esb[s3];
        float4 h0 = *(const float4*)&htb[(size_t)s0*32 + c*4];
        float4 h1 = *(const float4*)&htb[(size_t)s1*32 + c*4];
        float4 h2 = *(const float4*)&htb[(size_t)s2*32 + c*4];
        float4 h3 = *(const float4*)&htb[(size_t)s3*32 + c*4];
        int ni = i + 32;
        bool nv0 = ni      < cnt, nv1 = ni + 8  < cnt,
             nv2 = ni + 16 < cnt, nv3 = ni + 24 < cnt;
        int t0 = nv0 ? srcsort1[start + ni]      : 0;
        int t1 = nv1 ? srcsort1[start + ni + 8]  : 0;
        int t2 = nv2 ? srcsort1[start + ni + 16] : 0;
        int t3 = nv3 ? srcsort1[start + ni + 24] : 0;
        lg0 += edv; lg1 += edv; lg2 += edv; lg3 += edv;
        lg0 = lg0 > 0.f ? lg0 : NEG * lg0;
        lg1 = lg1 > 0.f ? lg1 : NEG * lg1;
        lg2 = lg2 > 0.f ? lg2 : NEG * lg2;
        lg3 = lg3 > 0.f ? lg3 : NEG * lg3;
        float w0 = v0 ? __expf(lg0) : 0.f;
        float w1 = v1 ? __expf(lg1) : 0.f;
        float w2 = v2 ? __expf(lg2) : 0.f;
        float w3 = v3 ? __expf(lg3) : 0.f;
        ax = fmaf(w0, h0.x, ax); ay = fmaf(w0, h0.y, ay);
        az = fmaf(w0, h0.z, az); aw = fmaf(w0, h0.w, aw);
        ax = fmaf(w1, h1.x, ax); ay = fmaf(w1, h1.y, ay);
        az = fmaf(w1, h1.z, az); aw = fmaf(w1, h1.w, aw);
        ax = fmaf(w2, h2.x, ax); ay = fmaf(w2, h2.y, ay);
        az = fmaf(w2, h2.z, az); aw = fmaf(w2, h2.w, aw);
        ax = fmaf(w3, h3.x, ax); ay = fmaf(w3, h3.y, ay);
        az = fmaf(w3, h3.z, az); aw = fmaf(w3, h3.w, aw);
        wsum += (w0 + w1) + (w2 + w3);
        i = ni; s0 = t0; s1 = t1; s2 = t2; s3 = t3;
        v0 = nv0; v1 = nv1; v2 = nv2; v3 = nv3;
        if (i >= cnt) break;
    }
    ax += __shfl_xor(ax, 8); ax += __shfl_xor(ax, 16); ax += __shfl_xor(ax, 32);
    ay += __shfl_xor(ay, 8); ay += __shfl_xor(ay, 16); ay += __shfl_xor(ay, 32);
    az += __shfl_xor(az, 8); az += __shfl_xor(az, 16); az += __shfl_xor(az, 32);
    aw += __shfl_xor(aw, 8); aw += __shfl_xor(aw, 16); aw += __shfl_xor(aw, 32);
    wsum += __shfl_xor(wsum, 8); wsum += __shfl_xor(wsum, 16); wsum += __shfl_xor(wsum, 32);
    if (grp == 0) {
        float inv = cnt > 0 ? 1.f / wsum : 0.f;
        float4 bb = *(const float4*)&b2[c*4];
        float4 o;
        o.x = ax*inv + bb.x; o.y = ay*inv + bb.y;
        o.z = az*inv + bb.z; o.w = aw*inv + bb.w;
        *(float4*)&outp[((size_t)(b*ND1 + d))*32 + c*4] = o;
    }
}

extern "C" void kernel_launch(void* const* d_in, const int* in_sizes, int n_in,
                              void* d_out, int out_size, void* d_ws, size_t ws_size,
                              hipStream_t stream) {
    const float* x        = (const float*)d_in[0];
    const int*   n_id0    = (const int*)d_in[1];
    const int*   res0     = (const int*)d_in[2];
    const int*   esrc0    = (const int*)d_in[3];
    const int*   edst0    = (const int*)d_in[4];
    const int*   res1     = (const int*)d_in[5];
    const int*   esrc1    = (const int*)d_in[6];
    const int*   edst1    = (const int*)d_in[7];
    const float* W1       = (const float*)d_in[8];
    const float* a_src1   = (const float*)d_in[9];
    const float* a_dst1   = (const float*)d_in[10];
    const float* b1       = (const float*)d_in[11];
    const float* W2       = (const float*)d_in[12];
    const float* a_src2   = (const float*)d_in[13];
    const float* a_dst2   = (const float*)d_in[14];
    const float* b2       = (const float*)d_in[15];
    float* outp = (float*)d_out;

    char* base = (char*)d_ws;
    unsigned short* ht1b = (unsigned short*)base;            // 120000*64*2  = 15,360,000 B
    float* es1  = (float*)(base + 15360000);                 // 960,000 f
    float* ed1  = es1 + 960000;                              // 960,000 f
    float* agg1 = ed1 + 960000;                              // 3,840,000 f
    float* ht2  = agg1 + 3840000;                            // 1,920,000 f
    float* es2  = ht2 + 1920000;                             // 60,000 f
    float* ed2  = es2 + 60000;                               // 60,000 f
    // deg0|deg1 contiguous so one memsetAsync zeroes both
    int* deg0     = (int*)(ed2 + 60000);                     // 15000
    int* deg1     = deg0 + ND0;                              // 7500
    int* off0     = deg1 + ND1;                              // 15000
    int* cur0     = off0 + ND0;                              // 15000
    int* off1     = cur0 + ND0;                              // 7500
    int* cur1     = off1 + ND1;                              // 7500
    int* srcsort0 = cur1 + ND1;                              // 360000
    int* srcsort1 = srcsort0 + NE0;                          // 180000
    // total ~49.2 MB

    hipMemsetAsync(deg0, 0, (ND0 + ND1) * sizeof(int), stream);
    kA_gemm_hist<<<K1B + HB, 256, 0, stream>>>(x, n_id0, W1, a_src1, a_dst1,
                                               ht1b, es1, ed1,
                                               edst0, edst1, deg0, deg1);
    ks_scan<<<2, 1024, 0, stream>>>(deg0, off0, cur0, deg1, off1, cur1);
    kc_scatter<<<(NE0 + NE1 + 255)/256, 256, 0, stream>>>(esrc0, edst0, esrc1, edst1,
                                                          cur0, cur1, srcsort0, srcsort1);
    k3_agg1<<<NB*(ND0/4), 256, 0, stream>>>(srcsort0, off0, deg0, res0, es1, ed1, ht1b, b1, agg1);
    k5_node2<<<(NB*ND0 + 127)/128, 256, 0, stream>>>(agg1, W2, a_src2, a_dst2, ht2, es2, ed2);
    k7_agg2<<<NB*(ND1/4), 256, 0, stream>>>(srcsort1, off1, deg1, res1, es2, ed2, ht2, b2, outp);
}